// Round 1
// baseline (541.713 us; speedup 1.0000x reference)
//
#include <hip/hip_runtime.h>
#include <math.h>

// Problem constants
#define B_    256
#define T_    2048
#define DIN   64
#define H_    32
#define C_    16

// Time-chunking: chunk length 128, burn-in 96.
// CHUNK=128 -> 2048 one-wave blocks = 2 waves/SIMD (was 1 at CHUNK=256):
// the second resident wave hides the LDS-allgather / u-load / tanh stalls
// that dominated the latency-bound step (~1600cy/step at VALUBusy 56%).
#define CHUNK 128
#define WARM  96
#define NCHUNK (T_ / CHUNK)   // 16

// Workspace layout (bytes).
#define OFF_WCOMB 0u
#define OFF_BCOMB 4096u
#define OFF_U     (1u << 20)   // u_enc: [B*T, H] fp32 = 64 MiB

__device__ __forceinline__ float fast_tanh(float x) {
    float e2 = __expf(x + x);
    return 1.0f - 2.0f * __builtin_amdgcn_rcpf(e2 + 1.0f);
}

// ---------------------------------------------------------------------------
// Prep: W_comb = W_co @ W_code  (H x H), b_comb = W_co @ b_code + b_co
// ---------------------------------------------------------------------------
__global__ __launch_bounds__(1024) void prep_kernel(
        const float* __restrict__ W_code, const float* __restrict__ b_code,
        const float* __restrict__ W_co,   const float* __restrict__ b_co,
        float* __restrict__ W_comb, float* __restrict__ b_comb) {
    int t = threadIdx.x;
    int i = t >> 5, j = t & 31;
    float s = 0.0f;
#pragma unroll
    for (int c = 0; c < C_; ++c)
        s += W_co[i * C_ + c] * W_code[c * H_ + j];
    W_comb[i * H_ + j] = s;
    if (t < H_) {
        float sb = b_co[t];
#pragma unroll
        for (int c = 0; c < C_; ++c)
            sb += W_co[t * C_ + c] * b_code[c];
        b_comb[t] = sb;
    }
}

// ---------------------------------------------------------------------------
// k1: u[r,i] = sum_d x[r,d]*W_in[i,d] + b_in[i] + b_res_enc[i]
// (b_res_enc folded in here so the scan step saves a register + an add.)
// 128-row x tile staged in LDS via coalesced float4 loads.
// ---------------------------------------------------------------------------
__global__ __launch_bounds__(256) void inproj_kernel(
        const float* __restrict__ x, const float* __restrict__ W_in,
        const float* __restrict__ b_in, const float* __restrict__ b_res_enc,
        float* __restrict__ u) {
    __shared__ __align__(16) float4 lx[128 * 16];   // 32 KiB: [row][k4]

    int tid  = threadIdx.x;
    int w    = tid >> 6;
    int lane = tid & 63;
    int i    = lane & 31;
    int par  = lane >> 5;

    // W_in row i -> registers (redundant across halves; L2-resident)
    float Wr[DIN];
    {
        const float4* wi4 = reinterpret_cast<const float4*>(W_in + i * DIN);
#pragma unroll
        for (int q = 0; q < DIN / 4; ++q) {
            float4 v = wi4[q];
            Wr[4*q+0] = v.x; Wr[4*q+1] = v.y; Wr[4*q+2] = v.z; Wr[4*q+3] = v.w;
        }
    }
    float bi = b_in[i] + b_res_enc[i];

    long row_base = (long)blockIdx.x * 128;
    const float4* xg = reinterpret_cast<const float4*>(x) + row_base * 16;

    // stage tile: 2048 float4, 256 threads -> 8 each, coalesced
#pragma unroll
    for (int k = 0; k < 8; ++k)
        lx[tid + 256 * k] = xg[tid + 256 * k];
    __syncthreads();

#pragma unroll
    for (int g = 0; g < 4; ++g) {
        int r0 = w * 32 + g * 8 + par;      // rows r0, r0+2, r0+4, r0+6
        float acc0 = 0.f, acc1 = 0.f, acc2 = 0.f, acc3 = 0.f;
#pragma unroll
        for (int k4 = 0; k4 < 16; ++k4) {
            float4 wv = { Wr[4*k4+0], Wr[4*k4+1], Wr[4*k4+2], Wr[4*k4+3] };
            float4 x0 = lx[(r0 + 0) * 16 + k4];
            float4 x1 = lx[(r0 + 2) * 16 + k4];
            float4 x2 = lx[(r0 + 4) * 16 + k4];
            float4 x3 = lx[(r0 + 6) * 16 + k4];
            acc0 += x0.x * wv.x + x0.y * wv.y + x0.z * wv.z + x0.w * wv.w;
            acc1 += x1.x * wv.x + x1.y * wv.y + x1.z * wv.z + x1.w * wv.w;
            acc2 += x2.x * wv.x + x2.y * wv.y + x2.z * wv.z + x2.w * wv.w;
            acc3 += x3.x * wv.x + x3.y * wv.y + x3.z * wv.z + x3.w * wv.w;
        }
        long rg = row_base + r0;
        u[(rg + 0) * H_ + i] = acc0 + bi;
        u[(rg + 2) * H_ + i] = acc1 + bi;
        u[(rg + 4) * H_ + i] = acc2 + bi;
        u[(rg + 6) * H_ + i] = acc3 + bi;
    }
}

// ---------------------------------------------------------------------------
// k2: fused enc-scan -> W_comb -> dec-scan -> READOUT, time-chunked w/ burn-in.
// One wave per block, lanes 0-31 = batch b0, 32-63 = b1 (same chunk).
// Software-pipelined step:
//   enc matvec -> write/ISSUE henc gather
//   -> (independent while it lands) Wd.hdec matvec + DEFERRED readout(t-1)
//      + u prefetch (2 steps ahead)
//   -> consume henc: comb matvec -> tanh -> write/ISSUE hdec gather
//      (consumed only after next step's enc matvec)
// Readout is unconditional in the main loop (peeled first iter) so W_ro rows
// stay register-resident instead of being re-loaded under a branch.
// ---------------------------------------------------------------------------
__device__ __forceinline__ float mv32(const float (&W)[H_], const float (&h)[H_],
                                      float init) {
    float a0 = init, a1 = 0.f, a2 = 0.f, a3 = 0.f;
#pragma unroll
    for (int j = 0; j < H_; j += 4) {
        a0 += W[j+0] * h[j+0];
        a1 += W[j+1] * h[j+1];
        a2 += W[j+2] * h[j+2];
        a3 += W[j+3] * h[j+3];
    }
    return (a0 + a1) + (a2 + a3);
}

__device__ __forceinline__ void gather32(const float (&src)[H_], float (&h)[H_]) {
#pragma unroll
    for (int q = 0; q < H_ / 4; ++q) {
        float4 v = *reinterpret_cast<const float4*>(&src[4 * q]);
        h[4*q+0] = v.x; h[4*q+1] = v.y; h[4*q+2] = v.z; h[4*q+3] = v.w;
    }
}

__device__ __forceinline__ void readout2(const float (&Wo0)[H_], const float (&Wo1)[H_],
                                         float bo0, float bo1, const float (&hd)[H_],
                                         float* dst) {
    float s00 = bo0, s01 = 0.f, s10 = bo1, s11 = 0.f;
#pragma unroll
    for (int j = 0; j < H_; j += 2) {
        s00 += Wo0[j]     * hd[j];
        s01 += Wo0[j + 1] * hd[j + 1];
        s10 += Wo1[j]     * hd[j];
        s11 += Wo1[j + 1] * hd[j + 1];
    }
    *reinterpret_cast<float2*>(dst) = make_float2(s00 + s01, s10 + s11);
}

__global__ __launch_bounds__(64, 2) void scan_kernel(
        const float* __restrict__ u,
        const float* __restrict__ W_res_enc,
        const float* __restrict__ W_res_dec, const float* __restrict__ b_res_dec,
        const float* __restrict__ W_comb,    const float* __restrict__ b_comb,
        const float* __restrict__ W_ro,      const float* __restrict__ b_ro,
        float* __restrict__ out) {
    int lane = threadIdx.x;
    int i = lane & 31;
    int half = lane >> 5;
    int b  = ((blockIdx.x & 127) << 1) | half;
    int c  = blockIdx.x >> 7;
    int t0 = c * CHUNK;
    int tstart = (c == 0) ? 0 : (t0 - WARM);
    int tend = t0 + CHUNK;

    float We[H_], Wc[H_], Wd[H_], Wo0[H_], Wo1[H_];
    {
        const float4* we4 = reinterpret_cast<const float4*>(W_res_enc + i * H_);
        const float4* wc4 = reinterpret_cast<const float4*>(W_comb + i * H_);
        const float4* wd4 = reinterpret_cast<const float4*>(W_res_dec + i * H_);
        const float4* wo0 = reinterpret_cast<const float4*>(W_ro + (2 * i) * H_);
        const float4* wo1 = reinterpret_cast<const float4*>(W_ro + (2 * i + 1) * H_);
#pragma unroll
        for (int q = 0; q < H_ / 4; ++q) {
            float4 a = we4[q], bq = wc4[q], d = wd4[q], o0 = wo0[q], o1 = wo1[q];
            We[4*q+0]=a.x;  We[4*q+1]=a.y;  We[4*q+2]=a.z;  We[4*q+3]=a.w;
            Wc[4*q+0]=bq.x; Wc[4*q+1]=bq.y; Wc[4*q+2]=bq.z; Wc[4*q+3]=bq.w;
            Wd[4*q+0]=d.x;  Wd[4*q+1]=d.y;  Wd[4*q+2]=d.z;  Wd[4*q+3]=d.w;
            Wo0[4*q+0]=o0.x;Wo0[4*q+1]=o0.y;Wo0[4*q+2]=o0.z;Wo0[4*q+3]=o0.w;
            Wo1[4*q+0]=o1.x;Wo1[4*q+1]=o1.y;Wo1[4*q+2]=o1.z;Wo1[4*q+3]=o1.w;
        }
    }
    float bcd = b_comb[i] + b_res_dec[i];
    float bo0 = b_ro[2 * i], bo1 = b_ro[2 * i + 1];

    float henc[H_], hdec[H_];
#pragma unroll
    for (int j = 0; j < H_; ++j) { henc[j] = 0.0f; hdec[j] = 0.0f; }

    __shared__ __align__(16) float lhe[2][H_];
    __shared__ __align__(16) float lhd[2][H_];

    const float* ub = u + ((long)b * T_) * H_ + i;
    float*       ob = out + ((long)b * T_) * DIN + 2 * i;

    // 2-deep u prefetch (b_in + b_res_enc already folded in by inproj)
    float ucur = ub[(long)tstart * H_];
    float un1  = ub[(long)(tstart + 1) * H_];

    // ---- burn-in: state settling only, no readout ----
    for (int t = tstart; t < t0; ++t) {
        float a = fast_tanh(mv32(We, henc, ucur));
        lhe[half][i] = a;
        gather32(lhe[half], henc);              // issue gather (in-order LDS)
        float dacc = mv32(Wd, hdec, 0.f);       // independent: hides gather
        ucur = un1;
        un1 = ub[(t + 2) * H_];                 // t+2 <= t0+1 < tend, always valid
        float d = fast_tanh(mv32(Wc, henc, bcd) + dacc);
        lhd[half][i] = d;
        gather32(lhd[half], hdec);              // consumed next step after enc
    }

    // ---- peeled t = t0 (no previous in-chunk step to read out) ----
    {
        float a = fast_tanh(mv32(We, henc, ucur));
        lhe[half][i] = a;
        gather32(lhe[half], henc);
        float dacc = mv32(Wd, hdec, 0.f);
        ucur = un1;
        un1 = ub[(t0 + 2) * H_];                // t0+2 < tend (CHUNK >= 4)
        float d = fast_tanh(mv32(Wc, henc, bcd) + dacc);
        lhd[half][i] = d;
        gather32(lhd[half], hdec);
    }

    // ---- main loop: unconditional deferred readout of t-1 ----
    for (int t = t0 + 1; t < tend; ++t) {
        float a = fast_tanh(mv32(We, henc, ucur));
        lhe[half][i] = a;
        gather32(lhe[half], henc);              // issue henc(t) gather
        float dacc = mv32(Wd, hdec, 0.f);       // uses hdec(t-1), independent
        readout2(Wo0, Wo1, bo0, bo1, hdec, ob + (long)(t - 1) * DIN);
        int tn = (t + 2 < tend) ? (t + 2) : (tend - 1);
        ucur = un1;
        un1 = ub[tn * H_];
        float d = fast_tanh(mv32(Wc, henc, bcd) + dacc);  // waits on henc gather
        lhd[half][i] = d;
        gather32(lhd[half], hdec);              // hidden by next step's enc matvec
    }
    readout2(Wo0, Wo1, bo0, bo1, hdec, ob + (long)(tend - 1) * DIN);
}

extern "C" void kernel_launch(void* const* d_in, const int* in_sizes, int n_in,
                              void* d_out, int out_size, void* d_ws, size_t ws_size,
                              hipStream_t stream) {
    const float* x         = (const float*)d_in[0];
    const float* W_in      = (const float*)d_in[1];
    const float* b_in      = (const float*)d_in[2];
    const float* W_res_enc = (const float*)d_in[3];
    const float* b_res_enc = (const float*)d_in[4];
    const float* W_code    = (const float*)d_in[5];
    const float* b_code    = (const float*)d_in[6];
    const float* W_co      = (const float*)d_in[7];
    const float* b_co      = (const float*)d_in[8];
    const float* W_res_dec = (const float*)d_in[9];
    const float* b_res_dec = (const float*)d_in[10];
    const float* W_ro      = (const float*)d_in[11];
    const float* b_ro      = (const float*)d_in[12];
    float* out = (float*)d_out;

    char* ws = (char*)d_ws;
    float* W_comb = (float*)(ws + OFF_WCOMB);
    float* b_comb = (float*)(ws + OFF_BCOMB);
    float* u      = (float*)(ws + OFF_U);

    prep_kernel<<<1, 1024, 0, stream>>>(W_code, b_code, W_co, b_co, W_comb, b_comb);
    inproj_kernel<<<(B_ * T_) / 128, 256, 0, stream>>>(x, W_in, b_in, b_res_enc, u);
    scan_kernel<<<(B_ / 2) * NCHUNK, 64, 0, stream>>>(u, W_res_enc,
                                                      W_res_dec, b_res_dec,
                                                      W_comb, b_comb, W_ro, b_ro, out);
}

// Round 3
// 533.866 us; speedup vs baseline: 1.0147x; 1.0147x over previous
//
#include <hip/hip_runtime.h>
#include <math.h>

// Problem constants
#define B_    256
#define T_    2048
#define DIN   64
#define H_    32
#define C_    16

// Time-chunking: chunk length 128, burn-in 96 -> 2048 one-wave blocks
// (2 waves/SIMD of available parallelism).
#define CHUNK 128
#define WARM  96
#define NCHUNK (T_ / CHUNK)   // 16

// Workspace layout (bytes) — stays within the proven ~65 MiB footprint.
// (Round-2 added a second 64 MiB buffer -> ~130 MiB total; the container
//  crash is consistent with ws overflow. hdec now aliases into `out`.)
#define OFF_WCOMB 0u
#define OFF_BCOMB 4096u
#define OFF_U     (1u << 20)   // u_enc: [B*T, H] fp32 = 64 MiB

__device__ __forceinline__ float fast_tanh(float x) {
    float e2 = __expf(x + x);
    return 1.0f - 2.0f * __builtin_amdgcn_rcpf(e2 + 1.0f);
}

// ---------------------------------------------------------------------------
// Prep: W_comb = W_co @ W_code  (H x H), b_comb = W_co @ b_code + b_co
// ---------------------------------------------------------------------------
__global__ __launch_bounds__(1024) void prep_kernel(
        const float* __restrict__ W_code, const float* __restrict__ b_code,
        const float* __restrict__ W_co,   const float* __restrict__ b_co,
        float* __restrict__ W_comb, float* __restrict__ b_comb) {
    int t = threadIdx.x;
    int i = t >> 5, j = t & 31;
    float s = 0.0f;
#pragma unroll
    for (int c = 0; c < C_; ++c)
        s += W_co[i * C_ + c] * W_code[c * H_ + j];
    W_comb[i * H_ + j] = s;
    if (t < H_) {
        float sb = b_co[t];
#pragma unroll
        for (int c = 0; c < C_; ++c)
            sb += W_co[t * C_ + c] * b_code[c];
        b_comb[t] = sb;
    }
}

// ---------------------------------------------------------------------------
// k1: u[r,i] = sum_d x[r,d]*W_in[i,d] + b_in[i] + b_res_enc[i]
// (b_res_enc folded in here so the scan step saves a register + an add.)
// 128-row x tile staged in LDS via coalesced float4 loads.
// ---------------------------------------------------------------------------
__global__ __launch_bounds__(256) void inproj_kernel(
        const float* __restrict__ x, const float* __restrict__ W_in,
        const float* __restrict__ b_in, const float* __restrict__ b_res_enc,
        float* __restrict__ u) {
    __shared__ __align__(16) float4 lx[128 * 16];   // 32 KiB: [row][k4]

    int tid  = threadIdx.x;
    int w    = tid >> 6;
    int lane = tid & 63;
    int i    = lane & 31;
    int par  = lane >> 5;

    // W_in row i -> registers (redundant across halves; L2-resident)
    float Wr[DIN];
    {
        const float4* wi4 = reinterpret_cast<const float4*>(W_in + i * DIN);
#pragma unroll
        for (int q = 0; q < DIN / 4; ++q) {
            float4 v = wi4[q];
            Wr[4*q+0] = v.x; Wr[4*q+1] = v.y; Wr[4*q+2] = v.z; Wr[4*q+3] = v.w;
        }
    }
    float bi = b_in[i] + b_res_enc[i];

    long row_base = (long)blockIdx.x * 128;
    const float4* xg = reinterpret_cast<const float4*>(x) + row_base * 16;

    // stage tile: 2048 float4, 256 threads -> 8 each, coalesced
#pragma unroll
    for (int k = 0; k < 8; ++k)
        lx[tid + 256 * k] = xg[tid + 256 * k];
    __syncthreads();

#pragma unroll
    for (int g = 0; g < 4; ++g) {
        int r0 = w * 32 + g * 8 + par;      // rows r0, r0+2, r0+4, r0+6
        float acc0 = 0.f, acc1 = 0.f, acc2 = 0.f, acc3 = 0.f;
#pragma unroll
        for (int k4 = 0; k4 < 16; ++k4) {
            float4 wv = { Wr[4*k4+0], Wr[4*k4+1], Wr[4*k4+2], Wr[4*k4+3] };
            float4 x0 = lx[(r0 + 0) * 16 + k4];
            float4 x1 = lx[(r0 + 2) * 16 + k4];
            float4 x2 = lx[(r0 + 4) * 16 + k4];
            float4 x3 = lx[(r0 + 6) * 16 + k4];
            acc0 += x0.x * wv.x + x0.y * wv.y + x0.z * wv.z + x0.w * wv.w;
            acc1 += x1.x * wv.x + x1.y * wv.y + x1.z * wv.z + x1.w * wv.w;
            acc2 += x2.x * wv.x + x2.y * wv.y + x2.z * wv.z + x2.w * wv.w;
            acc3 += x3.x * wv.x + x3.y * wv.y + x3.z * wv.z + x3.w * wv.w;
        }
        long rg = row_base + r0;
        u[(rg + 0) * H_ + i] = acc0 + bi;
        u[(rg + 2) * H_ + i] = acc1 + bi;
        u[(rg + 4) * H_ + i] = acc2 + bi;
        u[(rg + 6) * H_ + i] = acc3 + bi;
    }
}

// ---------------------------------------------------------------------------
// k2: fused enc-scan -> W_comb -> dec-scan, time-chunked w/ burn-in.
// NO readout here: live set = We/Wc/Wd (96) + henc/hdec (64) + ~15 misc,
// fits in registers with zero spill/remat (round-1 regression was a 109-reg
// scratch spill visible as +57 MB WRITE_SIZE). hdec states are written into
// the FIRST HALF of each `out` row ([r, 0:32)); readout is a separate
// memory-bound kernel that stages those rows before overwriting them.
// One wave per block, lanes 0-31 = batch b0, 32-63 = b1 (same chunk).
// ---------------------------------------------------------------------------
__device__ __forceinline__ float mv32(const float (&W)[H_], const float (&h)[H_],
                                      float init) {
    float a0 = init, a1 = 0.f, a2 = 0.f, a3 = 0.f;
#pragma unroll
    for (int j = 0; j < H_; j += 4) {
        a0 += W[j+0] * h[j+0];
        a1 += W[j+1] * h[j+1];
        a2 += W[j+2] * h[j+2];
        a3 += W[j+3] * h[j+3];
    }
    return (a0 + a1) + (a2 + a3);
}

__device__ __forceinline__ void gather32(const float (&src)[H_], float (&h)[H_]) {
#pragma unroll
    for (int q = 0; q < H_ / 4; ++q) {
        float4 v = *reinterpret_cast<const float4*>(&src[4 * q]);
        h[4*q+0] = v.x; h[4*q+1] = v.y; h[4*q+2] = v.z; h[4*q+3] = v.w;
    }
}

__global__ __launch_bounds__(64, 1) void scan_kernel(
        const float* __restrict__ u,
        const float* __restrict__ W_res_enc,
        const float* __restrict__ W_res_dec, const float* __restrict__ b_res_dec,
        const float* __restrict__ W_comb,    const float* __restrict__ b_comb,
        float* __restrict__ hd /* = out, row stride DIN, hdec in cols 0..31 */) {
    int lane = threadIdx.x;
    int i = lane & 31;
    int half = lane >> 5;
    int b  = ((blockIdx.x & 127) << 1) | half;
    int c  = blockIdx.x >> 7;
    int t0 = c * CHUNK;
    int tstart = (c == 0) ? 0 : (t0 - WARM);
    int tend = t0 + CHUNK;

    float We[H_], Wc[H_], Wd[H_];
    {
        const float4* we4 = reinterpret_cast<const float4*>(W_res_enc + i * H_);
        const float4* wc4 = reinterpret_cast<const float4*>(W_comb + i * H_);
        const float4* wd4 = reinterpret_cast<const float4*>(W_res_dec + i * H_);
#pragma unroll
        for (int q = 0; q < H_ / 4; ++q) {
            float4 a = we4[q], bq = wc4[q], d = wd4[q];
            We[4*q+0]=a.x;  We[4*q+1]=a.y;  We[4*q+2]=a.z;  We[4*q+3]=a.w;
            Wc[4*q+0]=bq.x; Wc[4*q+1]=bq.y; Wc[4*q+2]=bq.z; Wc[4*q+3]=bq.w;
            Wd[4*q+0]=d.x;  Wd[4*q+1]=d.y;  Wd[4*q+2]=d.z;  Wd[4*q+3]=d.w;
        }
    }
    float bcd = b_comb[i] + b_res_dec[i];

    float henc[H_], hdec[H_];
#pragma unroll
    for (int j = 0; j < H_; ++j) { henc[j] = 0.0f; hdec[j] = 0.0f; }

    __shared__ __align__(16) float lhe[2][H_];
    __shared__ __align__(16) float lhd[2][H_];

    const float* ub = u + ((long)b * T_) * H_ + i;
    float*       hb = hd + ((long)b * T_) * DIN + i;   // out[r, i], i<32

    // 3-deep u prefetch (b_in + b_res_enc already folded in by inproj)
    float ucur = ub[(long)tstart * H_];
    float un1  = ub[(long)(tstart + 1) * H_];
    float un2  = ub[(long)(tstart + 2) * H_];

    // ---- burn-in: state settling only, no store ----
    for (int t = tstart; t < t0; ++t) {
        float a = fast_tanh(mv32(We, henc, ucur));
        lhe[half][i] = a;
        gather32(lhe[half], henc);              // issue gather (in-order LDS)
        float dacc = mv32(Wd, hdec, 0.f);       // independent: hides gather
        ucur = un1; un1 = un2;
        un2 = ub[(t + 3) * H_];                 // t+3 <= t0+2 < tend, in range
        float d = fast_tanh(mv32(Wc, henc, bcd) + dacc);
        lhd[half][i] = d;
        gather32(lhd[half], hdec);              // consumed next step after enc
    }

    // ---- main: same step + fire-and-forget hdec store ----
    for (int t = t0; t < tend; ++t) {
        float a = fast_tanh(mv32(We, henc, ucur));
        lhe[half][i] = a;
        gather32(lhe[half], henc);
        float dacc = mv32(Wd, hdec, 0.f);
        int tn = t + 3; if (tn > tend - 1) tn = tend - 1;
        ucur = un1; un1 = un2;
        un2 = ub[(long)tn * H_];
        float d = fast_tanh(mv32(Wc, henc, bcd) + dacc);
        hb[(long)t * DIN] = d;                  // no dependency on gather below
        lhd[half][i] = d;
        gather32(lhd[half], hdec);
    }
}

// ---------------------------------------------------------------------------
// k3: out[r,o] = sum_j hd[r,j] * W_ro[o,j] + b_ro[o]   (memory-bound)
// hd lives in out[r, 0:32). Per 128-row block: stage those rows into LDS
// (reads), __syncthreads, then overwrite out[r, 0:64) (writes). Blocks own
// disjoint rows -> no cross-block race; same-stream kernels serialize.
// Lane o (64 lanes) holds W_ro row o in VGPRs; LDS reads are broadcasts.
// ---------------------------------------------------------------------------
__global__ __launch_bounds__(256) void outproj_kernel(
        const float* __restrict__ W_ro, const float* __restrict__ b_ro,
        float* __restrict__ out) {
    __shared__ __align__(16) float4 lh[128 * 8];    // 16 KiB: [row][q]

    int tid  = threadIdx.x;
    int w    = tid >> 6;
    int o    = tid & 63;

    float Wo[H_];
    {
        const float4* wo4 = reinterpret_cast<const float4*>(W_ro + o * H_);
#pragma unroll
        for (int q = 0; q < H_ / 4; ++q) {
            float4 v = wo4[q];
            Wo[4*q+0] = v.x; Wo[4*q+1] = v.y; Wo[4*q+2] = v.z; Wo[4*q+3] = v.w;
        }
    }
    float bo = b_ro[o];

    long row_base = (long)blockIdx.x * 128;
    const float4* hg = reinterpret_cast<const float4*>(out);

    // stage tile: 128 rows x 8 float4 (first half of each 16-float4 out row)
#pragma unroll
    for (int k = 0; k < 4; ++k) {
        int idx = tid + 256 * k;                 // 0..1023
        int r = idx >> 3, q = idx & 7;
        lh[idx] = hg[(row_base + r) * 16 + q];   // 128B-contiguous per 8 lanes
    }
    __syncthreads();

    float* ob = out + (row_base + (long)w * 32) * DIN + o;
#pragma unroll 4
    for (int r = 0; r < 32; ++r) {
        int rr = w * 32 + r;
        float s0 = bo, s1 = 0.f, s2 = 0.f, s3 = 0.f;
#pragma unroll
        for (int q = 0; q < 8; ++q) {
            float4 h4 = lh[rr * 8 + q];       // broadcast: all lanes same addr
            s0 += Wo[4*q+0] * h4.x;
            s1 += Wo[4*q+1] * h4.y;
            s2 += Wo[4*q+2] * h4.z;
            s3 += Wo[4*q+3] * h4.w;
        }
        __builtin_nontemporal_store((s0 + s1) + (s2 + s3), ob + (long)r * DIN);
    }
}

extern "C" void kernel_launch(void* const* d_in, const int* in_sizes, int n_in,
                              void* d_out, int out_size, void* d_ws, size_t ws_size,
                              hipStream_t stream) {
    const float* x         = (const float*)d_in[0];
    const float* W_in      = (const float*)d_in[1];
    const float* b_in      = (const float*)d_in[2];
    const float* W_res_enc = (const float*)d_in[3];
    const float* b_res_enc = (const float*)d_in[4];
    const float* W_code    = (const float*)d_in[5];
    const float* b_code    = (const float*)d_in[6];
    const float* W_co      = (const float*)d_in[7];
    const float* b_co      = (const float*)d_in[8];
    const float* W_res_dec = (const float*)d_in[9];
    const float* b_res_dec = (const float*)d_in[10];
    const float* W_ro      = (const float*)d_in[11];
    const float* b_ro      = (const float*)d_in[12];
    float* out = (float*)d_out;

    char* ws = (char*)d_ws;
    float* W_comb = (float*)(ws + OFF_WCOMB);
    float* b_comb = (float*)(ws + OFF_BCOMB);
    float* u      = (float*)(ws + OFF_U);

    prep_kernel<<<1, 1024, 0, stream>>>(W_code, b_code, W_co, b_co, W_comb, b_comb);
    inproj_kernel<<<(B_ * T_) / 128, 256, 0, stream>>>(x, W_in, b_in, b_res_enc, u);
    scan_kernel<<<(B_ / 2) * NCHUNK, 64, 0, stream>>>(u, W_res_enc,
                                                      W_res_dec, b_res_dec,
                                                      W_comb, b_comb, out);
    outproj_kernel<<<(B_ * T_) / 128, 256, 0, stream>>>(W_ro, b_ro, out);
}

// Round 4
// 494.190 us; speedup vs baseline: 1.0962x; 1.0803x over previous
//
#include <hip/hip_runtime.h>
#include <math.h>

// Problem constants
#define B_    256
#define T_    2048
#define DIN   64
#define H_    32
#define C_    16

// Time-chunking: chunk length 128, burn-in 96.
// One batch per 64-lane wave (split-row layout) -> B*NCHUNK = 4096 blocks.
#define CHUNK 128
#define WARM  96
#define NCHUNK (T_ / CHUNK)   // 16

// Workspace: u only (64 MiB). hdec aliases into out[:, 0:32).
#define OFF_U 0u

__device__ __forceinline__ float fast_tanh(float x) {
    float e2 = __expf(x + x);
    return 1.0f - 2.0f * __builtin_amdgcn_rcpf(e2 + 1.0f);
}

// ---------------------------------------------------------------------------
// k1: u[r,i] = sum_d x[r,d]*W_in[i,d] + b_in[i] + b_res_enc[i]
// 128-row x tile staged in LDS via coalesced float4 loads.  (unchanged)
// ---------------------------------------------------------------------------
__global__ __launch_bounds__(256) void inproj_kernel(
        const float* __restrict__ x, const float* __restrict__ W_in,
        const float* __restrict__ b_in, const float* __restrict__ b_res_enc,
        float* __restrict__ u) {
    __shared__ __align__(16) float4 lx[128 * 16];   // 32 KiB: [row][k4]

    int tid  = threadIdx.x;
    int w    = tid >> 6;
    int lane = tid & 63;
    int i    = lane & 31;
    int par  = lane >> 5;

    float Wr[DIN];
    {
        const float4* wi4 = reinterpret_cast<const float4*>(W_in + i * DIN);
#pragma unroll
        for (int q = 0; q < DIN / 4; ++q) {
            float4 v = wi4[q];
            Wr[4*q+0] = v.x; Wr[4*q+1] = v.y; Wr[4*q+2] = v.z; Wr[4*q+3] = v.w;
        }
    }
    float bi = b_in[i] + b_res_enc[i];

    long row_base = (long)blockIdx.x * 128;
    const float4* xg = reinterpret_cast<const float4*>(x) + row_base * 16;

#pragma unroll
    for (int k = 0; k < 8; ++k)
        lx[tid + 256 * k] = xg[tid + 256 * k];
    __syncthreads();

#pragma unroll
    for (int g = 0; g < 4; ++g) {
        int r0 = w * 32 + g * 8 + par;      // rows r0, r0+2, r0+4, r0+6
        float acc0 = 0.f, acc1 = 0.f, acc2 = 0.f, acc3 = 0.f;
#pragma unroll
        for (int k4 = 0; k4 < 16; ++k4) {
            float4 wv = { Wr[4*k4+0], Wr[4*k4+1], Wr[4*k4+2], Wr[4*k4+3] };
            float4 x0 = lx[(r0 + 0) * 16 + k4];
            float4 x1 = lx[(r0 + 2) * 16 + k4];
            float4 x2 = lx[(r0 + 4) * 16 + k4];
            float4 x3 = lx[(r0 + 6) * 16 + k4];
            acc0 += x0.x * wv.x + x0.y * wv.y + x0.z * wv.z + x0.w * wv.w;
            acc1 += x1.x * wv.x + x1.y * wv.y + x1.z * wv.z + x1.w * wv.w;
            acc2 += x2.x * wv.x + x2.y * wv.y + x2.z * wv.z + x2.w * wv.w;
            acc3 += x3.x * wv.x + x3.y * wv.y + x3.z * wv.z + x3.w * wv.w;
        }
        long rg = row_base + r0;
        u[(rg + 0) * H_ + i] = acc0 + bi;
        u[(rg + 2) * H_ + i] = acc1 + bi;
        u[(rg + 4) * H_ + i] = acc2 + bi;
        u[(rg + 6) * H_ + i] = acc3 + bi;
    }
}

// ---------------------------------------------------------------------------
// k2: fused enc-scan -> W_comb -> dec-scan, split-row layout.
// One batch per 64-lane wave. Lane (p,i), p=lane>>5, i=lane&31 holds
// HALF-rows W[i, p*16 : p*16+16] of We/Wc/Wd (48 regs) and half-states
// he/hd[p*16 : p*16+16] (32 regs)  ->  ~106 VGPR, under the 128 HW step
// (round-3's 144 VGPRs rounded up past 128 and halved residency).
// Matvec = 16-MAC partial + __shfl_xor(32) cross-half reduce; allgather =
// lds write + 4x ds_read_b128 of a half. W_comb computed per-block in the
// prologue (prep_kernel merged away).
// hdec is written to out[r, 0:32); outproj later reads then overwrites.
// ---------------------------------------------------------------------------
__global__ __launch_bounds__(64, 4) void scan_kernel(
        const float* __restrict__ u,
        const float* __restrict__ W_res_enc,
        const float* __restrict__ W_res_dec, const float* __restrict__ b_res_dec,
        const float* __restrict__ W_code, const float* __restrict__ b_code,
        const float* __restrict__ W_co,   const float* __restrict__ b_co,
        float* __restrict__ hd /* = out, row stride DIN, hdec in cols 0..31 */) {
    int lane = threadIdx.x;
    int i = lane & 31;            // row index
    int p = lane >> 5;            // column half: [p*16, p*16+16)
    int b = blockIdx.x & (B_ - 1);
    int c = blockIdx.x >> 8;
    int t0 = c * CHUNK;
    int tstart = (c == 0) ? 0 : (t0 - WARM);
    int tend = t0 + CHUNK;

    // --- stage W_code (16x32 = 2 KiB) in LDS for the W_comb prologue ---
    __shared__ __align__(16) float wcode[C_ * H_];
    {
        const float4* src = reinterpret_cast<const float4*>(W_code);
        float4* dst = reinterpret_cast<float4*>(wcode);
        dst[lane]      = src[lane];        // 128 float4, 64 lanes x 2
        dst[lane + 64] = src[lane + 64];
    }

    // --- load weight half-rows (once; L2-resident) ---
    float We[16], Wd[16], Wco_r[C_];
    {
        const float4* we4 = reinterpret_cast<const float4*>(W_res_enc + i * H_ + p * 16);
        const float4* wd4 = reinterpret_cast<const float4*>(W_res_dec + i * H_ + p * 16);
        const float4* wc4 = reinterpret_cast<const float4*>(W_co + i * C_);
#pragma unroll
        for (int q = 0; q < 4; ++q) {
            float4 a = we4[q], d = wd4[q], w = wc4[q];
            We[4*q+0]=a.x; We[4*q+1]=a.y; We[4*q+2]=a.z; We[4*q+3]=a.w;
            Wd[4*q+0]=d.x; Wd[4*q+1]=d.y; Wd[4*q+2]=d.z; Wd[4*q+3]=d.w;
            Wco_r[4*q+0]=w.x; Wco_r[4*q+1]=w.y; Wco_r[4*q+2]=w.z; Wco_r[4*q+3]=w.w;
        }
    }
    __syncthreads();

    // --- W_comb half-row: Wc[k] = sum_c W_co[i,c] * W_code[c, p*16+k] ---
    float Wc[16];
#pragma unroll
    for (int k = 0; k < 16; ++k) {
        float s = 0.f;
#pragma unroll
        for (int cc = 0; cc < C_; ++cc)
            s += Wco_r[cc] * wcode[cc * H_ + p * 16 + k];
        Wc[k] = s;
    }
    float bcd;   // b_comb[i] + b_res_dec[i]
    {
        float s = b_co[i] + b_res_dec[i];
#pragma unroll
        for (int cc = 0; cc < C_; ++cc)
            s += Wco_r[cc] * b_code[cc];
        bcd = s;
    }

    // --- states (half each) ---
    float he[16], hdv[16];
#pragma unroll
    for (int k = 0; k < 16; ++k) { he[k] = 0.f; hdv[k] = 0.f; }

    __shared__ __align__(16) float lhe[H_];
    __shared__ __align__(16) float lhd[H_];

    const float* ub = u  + ((long)b * T_) * H_ + i;    // both halves same addr
    float*       hb = hd + ((long)b * T_) * DIN + i;   // out[r, i], i<32

    // 3-deep u prefetch (b_in + b_res_enc folded in by inproj)
    float ucur = ub[(long)tstart * H_];
    float un1  = ub[(long)(tstart + 1) * H_];
    float un2  = ub[(long)(tstart + 2) * H_];

    // ---- burn-in: no store ----
    for (int t = tstart; t < t0; ++t) {
        float e0 = 0.f, e1 = 0.f, e2 = 0.f, e3 = 0.f;
#pragma unroll
        for (int k = 0; k < 16; k += 4) {
            e0 += We[k+0] * he[k+0];
            e1 += We[k+1] * he[k+1];
            e2 += We[k+2] * he[k+2];
            e3 += We[k+3] * he[k+3];
        }
        float ep = (e0 + e1) + (e2 + e3);
        float a = fast_tanh(ep + __shfl_xor(ep, 32) + ucur);
        lhe[i] = a;                          // both halves write same value
        __syncthreads();
        {
            const float4* s4 = reinterpret_cast<const float4*>(&lhe[p * 16]);
#pragma unroll
            for (int q = 0; q < 4; ++q) {
                float4 v = s4[q];
                he[4*q+0]=v.x; he[4*q+1]=v.y; he[4*q+2]=v.z; he[4*q+3]=v.w;
            }
        }
        float g0 = 0.f, g1 = 0.f, d0 = 0.f, d1 = 0.f;
#pragma unroll
        for (int k = 0; k < 16; k += 2) {
            g0 += Wc[k+0] * he[k+0];
            g1 += Wc[k+1] * he[k+1];
            d0 += Wd[k+0] * hdv[k+0];
            d1 += Wd[k+1] * hdv[k+1];
        }
        float part = (g0 + g1) + (d0 + d1);
        float d = fast_tanh(part + __shfl_xor(part, 32) + bcd);
        ucur = un1; un1 = un2;
        un2 = ub[(long)(t + 3) * H_];        // t+3 <= t0+2 < tend, in range
        lhd[i] = d;
        __syncthreads();
        {
            const float4* s4 = reinterpret_cast<const float4*>(&lhd[p * 16]);
#pragma unroll
            for (int q = 0; q < 4; ++q) {
                float4 v = s4[q];
                hdv[4*q+0]=v.x; hdv[4*q+1]=v.y; hdv[4*q+2]=v.z; hdv[4*q+3]=v.w;
            }
        }
    }

    // ---- main: + fire-and-forget hdec store by half 0 ----
    for (int t = t0; t < tend; ++t) {
        float e0 = 0.f, e1 = 0.f, e2 = 0.f, e3 = 0.f;
#pragma unroll
        for (int k = 0; k < 16; k += 4) {
            e0 += We[k+0] * he[k+0];
            e1 += We[k+1] * he[k+1];
            e2 += We[k+2] * he[k+2];
            e3 += We[k+3] * he[k+3];
        }
        float ep = (e0 + e1) + (e2 + e3);
        float a = fast_tanh(ep + __shfl_xor(ep, 32) + ucur);
        lhe[i] = a;
        __syncthreads();
        {
            const float4* s4 = reinterpret_cast<const float4*>(&lhe[p * 16]);
#pragma unroll
            for (int q = 0; q < 4; ++q) {
                float4 v = s4[q];
                he[4*q+0]=v.x; he[4*q+1]=v.y; he[4*q+2]=v.z; he[4*q+3]=v.w;
            }
        }
        float g0 = 0.f, g1 = 0.f, d0 = 0.f, d1 = 0.f;
#pragma unroll
        for (int k = 0; k < 16; k += 2) {
            g0 += Wc[k+0] * he[k+0];
            g1 += Wc[k+1] * he[k+1];
            d0 += Wd[k+0] * hdv[k+0];
            d1 += Wd[k+1] * hdv[k+1];
        }
        float part = (g0 + g1) + (d0 + d1);
        float d = fast_tanh(part + __shfl_xor(part, 32) + bcd);
        int tn = t + 3; if (tn > tend - 1) tn = tend - 1;
        ucur = un1; un1 = un2;
        un2 = ub[(long)tn * H_];
        if (p == 0) hb[(long)t * DIN] = d;   // coalesced 128B by lanes 0-31
        lhd[i] = d;
        __syncthreads();
        {
            const float4* s4 = reinterpret_cast<const float4*>(&lhd[p * 16]);
#pragma unroll
            for (int q = 0; q < 4; ++q) {
                float4 v = s4[q];
                hdv[4*q+0]=v.x; hdv[4*q+1]=v.y; hdv[4*q+2]=v.z; hdv[4*q+3]=v.w;
            }
        }
    }
}

// ---------------------------------------------------------------------------
// k3: out[r,o] = sum_j hd[r,j] * W_ro[o,j] + b_ro[o]   (memory-bound)
// hd lives in out[r, 0:32). Stage 128 rows into LDS, sync, overwrite.
// Blocks own disjoint rows; same-stream kernels serialize -> no race.
// ---------------------------------------------------------------------------
__global__ __launch_bounds__(256) void outproj_kernel(
        const float* __restrict__ W_ro, const float* __restrict__ b_ro,
        float* __restrict__ out) {
    __shared__ __align__(16) float4 lh[128 * 8];    // 16 KiB: [row][q]

    int tid  = threadIdx.x;
    int w    = tid >> 6;
    int o    = tid & 63;

    float Wo[H_];
    {
        const float4* wo4 = reinterpret_cast<const float4*>(W_ro + o * H_);
#pragma unroll
        for (int q = 0; q < H_ / 4; ++q) {
            float4 v = wo4[q];
            Wo[4*q+0] = v.x; Wo[4*q+1] = v.y; Wo[4*q+2] = v.z; Wo[4*q+3] = v.w;
        }
    }
    float bo = b_ro[o];

    long row_base = (long)blockIdx.x * 128;
    const float4* hg = reinterpret_cast<const float4*>(out);

#pragma unroll
    for (int k = 0; k < 4; ++k) {
        int idx = tid + 256 * k;                 // 0..1023
        int r = idx >> 3, q = idx & 7;
        lh[idx] = hg[(row_base + r) * 16 + q];   // first half of each out row
    }
    __syncthreads();

    float* ob = out + (row_base + (long)w * 32) * DIN + o;
#pragma unroll 4
    for (int r = 0; r < 32; ++r) {
        int rr = w * 32 + r;
        float s0 = bo, s1 = 0.f, s2 = 0.f, s3 = 0.f;
#pragma unroll
        for (int q = 0; q < 8; ++q) {
            float4 h4 = lh[rr * 8 + q];       // broadcast: all lanes same addr
            s0 += Wo[4*q+0] * h4.x;
            s1 += Wo[4*q+1] * h4.y;
            s2 += Wo[4*q+2] * h4.z;
            s3 += Wo[4*q+3] * h4.w;
        }
        __builtin_nontemporal_store((s0 + s1) + (s2 + s3), ob + (long)r * DIN);
    }
}

extern "C" void kernel_launch(void* const* d_in, const int* in_sizes, int n_in,
                              void* d_out, int out_size, void* d_ws, size_t ws_size,
                              hipStream_t stream) {
    const float* x         = (const float*)d_in[0];
    const float* W_in      = (const float*)d_in[1];
    const float* b_in      = (const float*)d_in[2];
    const float* W_res_enc = (const float*)d_in[3];
    const float* b_res_enc = (const float*)d_in[4];
    const float* W_code    = (const float*)d_in[5];
    const float* b_code    = (const float*)d_in[6];
    const float* W_co      = (const float*)d_in[7];
    const float* b_co      = (const float*)d_in[8];
    const float* W_res_dec = (const float*)d_in[9];
    const float* b_res_dec = (const float*)d_in[10];
    const float* W_ro      = (const float*)d_in[11];
    const float* b_ro      = (const float*)d_in[12];
    float* out = (float*)d_out;

    float* u = (float*)((char*)d_ws + OFF_U);

    inproj_kernel<<<(B_ * T_) / 128, 256, 0, stream>>>(x, W_in, b_in, b_res_enc, u);
    scan_kernel<<<B_ * NCHUNK, 64, 0, stream>>>(u, W_res_enc,
                                                W_res_dec, b_res_dec,
                                                W_code, b_code, W_co, b_co, out);
    outproj_kernel<<<(B_ * T_) / 128, 256, 0, stream>>>(W_ro, b_ro, out);
}